// Round 7
// baseline (297.865 us; speedup 1.0000x reference)
//
#include <hip/hip_runtime.h>
#include <math.h>

#define BB 2
#define HH 16
#define QQ 2048
#define SS 4096
#define DD 64
#define NRH 16    // half of N_ROTATE=32
#define NQT128 16 // q-tiles of 128 per bh

typedef unsigned short u16;
typedef unsigned int   u32;
typedef short bhalf8 __attribute__((ext_vector_type(8)));  // 8 bf16 bit patterns
typedef float f32x4  __attribute__((ext_vector_type(4)));

typedef __attribute__((address_space(1))) const u32 gu32;
typedef __attribute__((address_space(3))) u32 lu32;

#if __has_builtin(__builtin_amdgcn_exp2f)
#define EXP2(x) __builtin_amdgcn_exp2f(x)
#else
#define EXP2(x) exp2f(x)
#endif

union Frag16 { uint4 u; bhalf8 v; u16 s[8]; uint2 d[2]; };

__device__ __forceinline__ u16 f2bf(float f) {  // RNE f32->bf16
  union { float f; u32 u; } c; c.f = f;
  return (u16)((c.u + 0x7FFFu + ((c.u >> 16) & 1u)) >> 16);
}

// packed RNE f32x2 -> bf16x2 (lo = first src)
__device__ __forceinline__ u32 cvt_pk_bf16(float lo, float hi) {
  u32 r;
  asm("v_cvt_pk_bf16_f32 %0, %1, %2" : "=v"(r) : "v"(lo), "v"(hi));
  return r;
}

__device__ __forceinline__ bhalf8 ldfrag(const u16* p) {
  Frag16 f; f.u = *reinterpret_cast<const uint4*>(p); return f.v;
}

__device__ __forceinline__ void rope32(float* x, int pos) {
  const float step = 0.8304820237218405f;  // log2(10000)/16
  const float fp = (float)pos;
#pragma unroll
  for (int i = 0; i < NRH; ++i) {
    float ang = fp * exp2f(-step * (float)i);
    float sv, cv;
    __sincosf(ang, &sv, &cv);
    float a = x[i], b = x[i + NRH];
    x[i]       = a * cv - b * sv;
    x[i + NRH] = b * cv + a * sv;
  }
}

// ---------------------------------------------------------------------------
// idx[b][0..2047] = ascending indices of true entries of skip_mask[b].
// ---------------------------------------------------------------------------
__global__ void prep_idx_kernel(const unsigned char* __restrict__ sm,
                                int* __restrict__ idx) {
  __shared__ int wsum[4];
  __shared__ int modes;
  const int tid = threadIdx.x;  // 256
  const int b = (int)blockIdx.x;

  int c = 0;
  for (int i = 0; i < 32; ++i) c += (sm[tid * 32 + i] != 0) ? 1 : 0;
#pragma unroll
  for (int off = 32; off; off >>= 1) c += __shfl_down(c, off);
  if ((tid & 63) == 0) wsum[tid >> 6] = c;
  __syncthreads();
  if (tid == 0) modes = (wsum[0] + wsum[1] + wsum[2] + wsum[3] > 3000) ? 1 : 0;
  __syncthreads();
  const bool byteMode = (modes != 0);
  const u32* sm32 = (const u32*)sm;

  const int base = b * SS + tid * 16;
  u32 flags = 0;
  for (int i = 0; i < 16; ++i) {
    bool f = byteMode ? (sm[base + i] != 0) : (sm32[base + i] != 0);
    flags |= ((u32)(f ? 1 : 0)) << i;
  }
  int cnt = __popc(flags);
  int vv = cnt;
#pragma unroll
  for (int off = 1; off < 64; off <<= 1) {
    int t = __shfl_up(vv, off);
    if ((tid & 63) >= off) vv += t;
  }
  __syncthreads();
  if ((tid & 63) == 63) wsum[tid >> 6] = vv;
  __syncthreads();
  int add = 0;
  for (int w2 = 0; w2 < (tid >> 6); ++w2) add += wsum[w2];
  int p = vv - cnt + add;
  for (int i = 0; i < 16; ++i) {
    if (flags & (1u << i)) {
      if (p < QQ) idx[b * QQ + p] = tid * 16 + i;
      ++p;
    }
  }
}

// ---------------------------------------------------------------------------
// Fused: blocks [0,512): k -> RoPE(pos=j) -> bf16 kbf[bh][j][d]
//        blocks [512,2560): v -> bf16 transposed vt[bh][d][p] with key
//        permutation kappa(p) = (p&32)|((p&4)<<2)|((p>>1)&12)|(p&3) within
//        each 64-key tile (matches swapped-QK^T in-register P^T fragments).
// ---------------------------------------------------------------------------
__global__ __launch_bounds__(256) void prep_kv_kernel(const float* __restrict__ k,
                                                      const float* __restrict__ v,
                                                      u16* __restrict__ kbf,
                                                      u16* __restrict__ vt) {
  __shared__ u16 tile[64][72];
  if (blockIdx.x < 512) {
    int r = blockIdx.x * 256 + threadIdx.x;  // 0..131071
    int pos = r & (SS - 1);
    float x[64];
    const float4* src = (const float4*)(k + (size_t)r * DD);
#pragma unroll
    for (int i = 0; i < 16; ++i) {
      float4 t = src[i];
      x[4 * i] = t.x; x[4 * i + 1] = t.y; x[4 * i + 2] = t.z; x[4 * i + 3] = t.w;
    }
    rope32(x, pos);
    u16 tmp[64];
#pragma unroll
    for (int i = 0; i < 64; ++i) tmp[i] = f2bf(x[i]);
    uint4* dst = (uint4*)(kbf + (size_t)r * DD);
#pragma unroll
    for (int i = 0; i < 8; ++i) dst[i] = ((uint4*)tmp)[i];
  } else {
    int blk = (int)blockIdx.x - 512;
    int bh = blk >> 6;
    int jt = blk & 63;
    int t = threadIdx.x;
    int jl = t >> 2;
    int dc = (t & 3) * 16;
    const float4* src = (const float4*)(v + ((size_t)(bh * SS + jt * 64 + jl)) * DD + dc);
#pragma unroll
    for (int i = 0; i < 4; ++i) {
      float4 f = src[i];
      tile[jl][dc + 4 * i]     = f2bf(f.x);
      tile[jl][dc + 4 * i + 1] = f2bf(f.y);
      tile[jl][dc + 4 * i + 2] = f2bf(f.z);
      tile[jl][dc + 4 * i + 3] = f2bf(f.w);
    }
    __syncthreads();
    int d = t >> 2;
    int c = t & 3;            // output positions c*16 .. c*16+15
    u16 o[16];
#pragma unroll
    for (int m = 0; m < 16; ++m) {  // position p holds key kappa(p)
      int p = c * 16 + m;
      int kp = (p & 32) | ((p & 4) << 2) | ((p >> 1) & 12) | (p & 3);
      o[m] = tile[kp][d];
    }
    uint4* dst = (uint4*)(vt + ((size_t)(bh * DD + d)) * SS + jt * 64 + c * 16);
    dst[0] = ((uint4*)o)[0];
    dst[1] = ((uint4*)o)[1];
  }
}

// ---------------------------------------------------------------------------
// Staging: one 64-key K tile + matching V^T tile into LDS via global_load_lds
// (16B/lane), XOR swizzle applied on the GLOBAL address side.
// ---------------------------------------------------------------------------
__device__ __forceinline__ void stage_tiles(const char* kb_bh, const char* vt_bh,
                                            u16* Kb, u16* Vb, int t0,
                                            int w, int srow, int schk) {
#pragma unroll
  for (int p2 = 0; p2 < 2; ++p2) {
    const int rr = w * 16 + p2 * 8 + srow;
    {
      const char* g = kb_bh + (size_t)(t0 + rr) * 128 + ((schk ^ (rr & 7)) * 16);
      lu32* l = (lu32*)((char*)Kb + (w * 16 + p2 * 8) * 128);
      __builtin_amdgcn_global_load_lds((gu32*)g, l, 16, 0, 0);
    }
    {
      const char* g = vt_bh + (size_t)rr * (SS * 2) + t0 * 2 + ((schk ^ (rr & 7)) * 16);
      lu32* l = (lu32*)((char*)Vb + (w * 16 + p2 * 8) * 128);
      __builtin_amdgcn_global_load_lds((gu32*)g, l, 16, 0, 0);
    }
  }
}

// ---------------------------------------------------------------------------
// One 64-key tile, one wave, 32 q rows (halves A/B = rows +0/+16), SWAPPED
// OPERANDS. Every K/V B-side LDS fragment feeds TWO MFMAs (A and B halves).
// P^T lives entirely in registers (cvt_pk packs) — no LDS P, no fence.
// ---------------------------------------------------------------------------
template <bool MASKED>
__device__ __forceinline__ void attn_tile(
    const u16* __restrict__ Kb, const u16* __restrict__ Vb,
    int t0, int grp, int col, int bndA, int bndB,
    bhalf8 qaA0, bhalf8 qaA1, bhalf8 qaB0, bhalf8 qaB1,
    f32x4& accA0, f32x4& accA1, f32x4& accA2, f32x4& accA3,
    f32x4& accB0, f32x4& accB1, f32x4& accB2, f32x4& accB3,
    float& lsumA, float& lsumB) {
  const int swz = col & 7;
  f32x4 z = {0.f, 0.f, 0.f, 0.f};
  f32x4 sA0 = z, sA1 = z, sA2 = z, sA3 = z;
  f32x4 sB0 = z, sB1 = z, sB2 = z, sB3 = z;
  {
    const u16* kr0 = Kb + (0 * 16 + col) * 64;
    const u16* kr1 = Kb + (1 * 16 + col) * 64;
    const u16* kr2 = Kb + (2 * 16 + col) * 64;
    const u16* kr3 = Kb + (3 * 16 + col) * 64;
    __builtin_amdgcn_s_setprio(1);
    bhalf8 a0 = ldfrag(kr0 + ((grp ^ swz) * 8));
    sA0 = __builtin_amdgcn_mfma_f32_16x16x32_bf16(a0, qaA0, sA0, 0, 0, 0);
    sB0 = __builtin_amdgcn_mfma_f32_16x16x32_bf16(a0, qaB0, sB0, 0, 0, 0);
    bhalf8 b0 = ldfrag(kr0 + (((4 + grp) ^ swz) * 8));
    sA0 = __builtin_amdgcn_mfma_f32_16x16x32_bf16(b0, qaA1, sA0, 0, 0, 0);
    sB0 = __builtin_amdgcn_mfma_f32_16x16x32_bf16(b0, qaB1, sB0, 0, 0, 0);
    bhalf8 a1 = ldfrag(kr1 + ((grp ^ swz) * 8));
    sA1 = __builtin_amdgcn_mfma_f32_16x16x32_bf16(a1, qaA0, sA1, 0, 0, 0);
    sB1 = __builtin_amdgcn_mfma_f32_16x16x32_bf16(a1, qaB0, sB1, 0, 0, 0);
    bhalf8 b1 = ldfrag(kr1 + (((4 + grp) ^ swz) * 8));
    sA1 = __builtin_amdgcn_mfma_f32_16x16x32_bf16(b1, qaA1, sA1, 0, 0, 0);
    sB1 = __builtin_amdgcn_mfma_f32_16x16x32_bf16(b1, qaB1, sB1, 0, 0, 0);
    bhalf8 a2 = ldfrag(kr2 + ((grp ^ swz) * 8));
    sA2 = __builtin_amdgcn_mfma_f32_16x16x32_bf16(a2, qaA0, sA2, 0, 0, 0);
    sB2 = __builtin_amdgcn_mfma_f32_16x16x32_bf16(a2, qaB0, sB2, 0, 0, 0);
    bhalf8 b2 = ldfrag(kr2 + (((4 + grp) ^ swz) * 8));
    sA2 = __builtin_amdgcn_mfma_f32_16x16x32_bf16(b2, qaA1, sA2, 0, 0, 0);
    sB2 = __builtin_amdgcn_mfma_f32_16x16x32_bf16(b2, qaB1, sB2, 0, 0, 0);
    bhalf8 a3 = ldfrag(kr3 + ((grp ^ swz) * 8));
    sA3 = __builtin_amdgcn_mfma_f32_16x16x32_bf16(a3, qaA0, sA3, 0, 0, 0);
    sB3 = __builtin_amdgcn_mfma_f32_16x16x32_bf16(a3, qaB0, sB3, 0, 0, 0);
    bhalf8 b3 = ldfrag(kr3 + (((4 + grp) ^ swz) * 8));
    sA3 = __builtin_amdgcn_mfma_f32_16x16x32_bf16(b3, qaA1, sA3, 0, 0, 0);
    sB3 = __builtin_amdgcn_mfma_f32_16x16x32_bf16(b3, qaB1, sB3, 0, 0, 0);
    __builtin_amdgcn_s_setprio(0);
  }

  // softmax (fixed-max exp2(s-16), exact) + pack P^T into PV B-frags in-lane
  uint2 wA0, wA1, wA2, wA3, wB0, wB1, wB2, wB3;
#define SM_C(SC, CB, BND, LS, W)                                               \
  {                                                                            \
    float p0, p1, p2v, p3;                                                     \
    const int kb = t0 + (CB) + grp * 4;                                        \
    if (MASKED) {                                                              \
      p0  = (kb + 0 <= (BND)) ? EXP2(SC[0] - 16.f) : 0.f;                      \
      p1  = (kb + 1 <= (BND)) ? EXP2(SC[1] - 16.f) : 0.f;                      \
      p2v = (kb + 2 <= (BND)) ? EXP2(SC[2] - 16.f) : 0.f;                      \
      p3  = (kb + 3 <= (BND)) ? EXP2(SC[3] - 16.f) : 0.f;                      \
    } else {                                                                   \
      p0  = EXP2(SC[0] - 16.f);                                                \
      p1  = EXP2(SC[1] - 16.f);                                                \
      p2v = EXP2(SC[2] - 16.f);                                                \
      p3  = EXP2(SC[3] - 16.f);                                                \
    }                                                                          \
    (LS) += (p0 + p1) + (p2v + p3);                                            \
    W.x = cvt_pk_bf16(p0, p1);                                                 \
    W.y = cvt_pk_bf16(p2v, p3);                                                \
  }
  SM_C(sA0, 0,  bndA, lsumA, wA0)
  SM_C(sA1, 16, bndA, lsumA, wA1)
  SM_C(sA2, 32, bndA, lsumA, wA2)
  SM_C(sA3, 48, bndA, lsumA, wA3)
  SM_C(sB0, 0,  bndB, lsumB, wB0)
  SM_C(sB1, 16, bndB, lsumB, wB1)
  SM_C(sB2, 32, bndB, lsumB, wB2)
  SM_C(sB3, 48, bndB, lsumB, wB3)
#undef SM_C

  bhalf8 pvA0, pvA1, pvB0, pvB1;
  {
    Frag16 f0, f1, g0, g1;
    f0.d[0] = wA0; f0.d[1] = wA1;
    f1.d[0] = wA2; f1.d[1] = wA3;
    g0.d[0] = wB0; g0.d[1] = wB1;
    g1.d[0] = wB2; g1.d[1] = wB3;
    pvA0 = f0.v; pvA1 = f1.v; pvB0 = g0.v; pvB1 = g1.v;
  }

  {
    const u16* vr0 = Vb + (0  + col) * 64;
    const u16* vr1 = Vb + (16 + col) * 64;
    const u16* vr2 = Vb + (32 + col) * 64;
    const u16* vr3 = Vb + (48 + col) * 64;
    __builtin_amdgcn_s_setprio(1);
    bhalf8 x0 = ldfrag(vr0 + ((grp ^ swz) * 8));
    accA0 = __builtin_amdgcn_mfma_f32_16x16x32_bf16(x0, pvA0, accA0, 0, 0, 0);
    accB0 = __builtin_amdgcn_mfma_f32_16x16x32_bf16(x0, pvB0, accB0, 0, 0, 0);
    bhalf8 y0 = ldfrag(vr0 + (((4 + grp) ^ swz) * 8));
    accA0 = __builtin_amdgcn_mfma_f32_16x16x32_bf16(y0, pvA1, accA0, 0, 0, 0);
    accB0 = __builtin_amdgcn_mfma_f32_16x16x32_bf16(y0, pvB1, accB0, 0, 0, 0);
    bhalf8 x1 = ldfrag(vr1 + ((grp ^ swz) * 8));
    accA1 = __builtin_amdgcn_mfma_f32_16x16x32_bf16(x1, pvA0, accA1, 0, 0, 0);
    accB1 = __builtin_amdgcn_mfma_f32_16x16x32_bf16(x1, pvB0, accB1, 0, 0, 0);
    bhalf8 y1 = ldfrag(vr1 + (((4 + grp) ^ swz) * 8));
    accA1 = __builtin_amdgcn_mfma_f32_16x16x32_bf16(y1, pvA1, accA1, 0, 0, 0);
    accB1 = __builtin_amdgcn_mfma_f32_16x16x32_bf16(y1, pvB1, accB1, 0, 0, 0);
    bhalf8 x2 = ldfrag(vr2 + ((grp ^ swz) * 8));
    accA2 = __builtin_amdgcn_mfma_f32_16x16x32_bf16(x2, pvA0, accA2, 0, 0, 0);
    accB2 = __builtin_amdgcn_mfma_f32_16x16x32_bf16(x2, pvB0, accB2, 0, 0, 0);
    bhalf8 y2 = ldfrag(vr2 + (((4 + grp) ^ swz) * 8));
    accA2 = __builtin_amdgcn_mfma_f32_16x16x32_bf16(y2, pvA1, accA2, 0, 0, 0);
    accB2 = __builtin_amdgcn_mfma_f32_16x16x32_bf16(y2, pvB1, accB2, 0, 0, 0);
    bhalf8 x3 = ldfrag(vr3 + ((grp ^ swz) * 8));
    accA3 = __builtin_amdgcn_mfma_f32_16x16x32_bf16(x3, pvA0, accA3, 0, 0, 0);
    accB3 = __builtin_amdgcn_mfma_f32_16x16x32_bf16(x3, pvB0, accB3, 0, 0, 0);
    bhalf8 y3 = ldfrag(vr3 + (((4 + grp) ^ swz) * 8));
    accA3 = __builtin_amdgcn_mfma_f32_16x16x32_bf16(y3, pvA1, accA3, 0, 0, 0);
    accB3 = __builtin_amdgcn_mfma_f32_16x16x32_bf16(y3, pvB1, accB3, 0, 0, 0);
    __builtin_amdgcn_s_setprio(0);
  }
}

// ---------------------------------------------------------------------------
// Flash attention. Block = 256 thr (4 waves), Q-tile 128 (32 q/wave = halves
// A/B), K-tile 64. Grid = 512 = 16 ranks x 32 bh; rank->qt pairs heavy+light
// (co-resident work constant). LDS = 32 KiB (K/V dbuf only — NO P buffer,
// NO fence). Every K/V frag read feeds 2 MFMAs.
// ---------------------------------------------------------------------------
__global__ __launch_bounds__(256) void attn_mfma_kernel(
    const float* __restrict__ qsrc, const u16* __restrict__ kbf,
    const u16* __restrict__ vt, const int* __restrict__ idx,
    float* __restrict__ out) {
  __shared__ u16 KbufA[64 * 64];
  __shared__ u16 VbufA[64 * 64];
  __shared__ u16 KbufB[64 * 64];
  __shared__ u16 VbufB[64 * 64];

  const int blk = (int)blockIdx.x;   // 512 = 16 ranks x 32 bh (bh fastest)
  const int bh  = blk & 31;
  const int rank = blk >> 5;         // 0..15
  // ranks 0..7 -> {15,13,11,9,7,5,3,1}; ranks 8..15 -> {0,2,4,6,8,10,12,14}
  const int qt  = (rank < 8) ? (15 - 2 * rank) : (2 * (rank - 8));
  const int q0  = qt * 128;
  const int b   = bh >> 4;
  const int tid  = threadIdx.x;
  const int w    = tid >> 6;
  const int lane = tid & 63;
  const int grp  = lane >> 4;
  const int col  = lane & 15;

  const char* kb_bh = (const char*)(kbf + (size_t)bh * SS * DD);
  const char* vt_bh = (const char*)(vt + (size_t)bh * DD * SS);

  const int srow = lane >> 3;
  const int schk = lane & 7;

  const int* idxb = idx + b * QQ + q0;
  const int bndA = idxb[w * 32 + col];        // lane's A-row bound (= RoPE pos)
  const int bndB = idxb[w * 32 + 16 + col];   // lane's B-row bound
  const int wave_minb = idxb[w * 32];         // ascending -> wave min bound
  const int wave_maxb = idxb[w * 32 + 31];    // wave max bound
  const int maxbound  = idxb[127];
  const int ntiles = (maxbound >> 6) + 1;

  // ---- inline q RoPE -> fragments (round-6 verified text, twice) ----
  bhalf8 qaA0, qaA1, qaB0, qaB1;
  {
    const int qrow = q0 + w * 32 + col;         // A half
    const float* qr = qsrc + (size_t)(bh * QQ + qrow) * DD;
    const int lof = (grp & 1) * 8;
    float4 A0 = *(const float4*)(qr + lof);
    float4 A1 = *(const float4*)(qr + lof + 4);
    float4 B0 = *(const float4*)(qr + 16 + lof);
    float4 B1 = *(const float4*)(qr + 16 + lof + 4);
    float4 C0 = *(const float4*)(qr + 32 + grp * 8);
    float4 C1 = *(const float4*)(qr + 32 + grp * 8 + 4);
    float xlo[8] = {A0.x, A0.y, A0.z, A0.w, A1.x, A1.y, A1.z, A1.w};
    float xhi[8] = {B0.x, B0.y, B0.z, B0.w, B1.x, B1.y, B1.z, B1.w};
    float xq1[8] = {C0.x, C0.y, C0.z, C0.w, C1.x, C1.y, C1.z, C1.w};
    const float scq = 0.125f * 1.44269504088896f;  // 1/sqrt(64) * log2(e)
    const float fp = (float)bndA;
    Frag16 f0, f1;
#pragma unroll
    for (int j = 0; j < 8; ++j) {
      float ang = fp * exp2f(-0.8304820237218405f * (float)(lof + j));
      float sv, cv;
      __sincosf(ang, &sv, &cv);
      float val = (grp >= 2) ? (xhi[j] * cv + xlo[j] * sv)
                             : (xlo[j] * cv - xhi[j] * sv);
      f0.s[j] = f2bf(val * scq);
      f1.s[j] = f2bf(xq1[j] * scq);
    }
    qaA0 = f0.v; qaA1 = f1.v;
  }
  {
    const int qrow = q0 + w * 32 + 16 + col;    // B half
    const float* qr = qsrc + (size_t)(bh * QQ + qrow) * DD;
    const int lof = (grp & 1) * 8;
    float4 A0 = *(const float4*)(qr + lof);
    float4 A1 = *(const float4*)(qr + lof + 4);
    float4 B0 = *(const float4*)(qr + 16 + lof);
    float4 B1 = *(const float4*)(qr + 16 + lof + 4);
    float4 C0 = *(const float4*)(qr + 32 + grp * 8);
    float4 C1 = *(const float4*)(qr + 32 + grp * 8 + 4);
    float xlo[8] = {A0.x, A0.y, A0.z, A0.w, A1.x, A1.y, A1.z, A1.w};
    float xhi[8] = {B0.x, B0.y, B0.z, B0.w, B1.x, B1.y, B1.z, B1.w};
    float xq1[8] = {C0.x, C0.y, C0.z, C0.w, C1.x, C1.y, C1.z, C1.w};
    const float scq = 0.125f * 1.44269504088896f;
    const float fp = (float)bndB;
    Frag16 f0, f1;
#pragma unroll
    for (int j = 0; j < 8; ++j) {
      float ang = fp * exp2f(-0.8304820237218405f * (float)(lof + j));
      float sv, cv;
      __sincosf(ang, &sv, &cv);
      float val = (grp >= 2) ? (xhi[j] * cv + xlo[j] * sv)
                             : (xlo[j] * cv - xhi[j] * sv);
      f0.s[j] = f2bf(val * scq);
      f1.s[j] = f2bf(xq1[j] * scq);
    }
    qaB0 = f0.v; qaB1 = f1.v;
  }

  f32x4 z = {0.f, 0.f, 0.f, 0.f};
  f32x4 accA0 = z, accA1 = z, accA2 = z, accA3 = z;
  f32x4 accB0 = z, accB1 = z, accB2 = z, accB3 = z;
  float lsumA = 0.f, lsumB = 0.f;

#define ATTN_CALL(M, KB, VB, T0)                                               \
  attn_tile<M>(KB, VB, T0, grp, col, bndA, bndB, qaA0, qaA1, qaB0, qaB1,       \
               accA0, accA1, accA2, accA3, accB0, accB1, accB2, accB3,         \
               lsumA, lsumB)

  stage_tiles(kb_bh, vt_bh, KbufA, VbufA, 0, w, srow, schk);
  __syncthreads();

  for (int ti = 0; ti < ntiles; ti += 2) {
    const bool has1 = (ti + 1) < ntiles;
    if (has1) stage_tiles(kb_bh, vt_bh, KbufB, VbufB, (ti + 1) << 6, w, srow, schk);
    {
      const int t0 = ti << 6;
      if (t0 <= wave_maxb) {   // wave-uniform; skipped tiles contribute zero P
        if (t0 + 63 <= wave_minb) ATTN_CALL(false, KbufA, VbufA, t0);
        else                      ATTN_CALL(true,  KbufA, VbufA, t0);
      }
    }
    __syncthreads();
    if (has1) {
      if (ti + 2 < ntiles)
        stage_tiles(kb_bh, vt_bh, KbufA, VbufA, (ti + 2) << 6, w, srow, schk);
      {
        const int t0 = (ti + 1) << 6;
        if (t0 <= wave_maxb) {
          if (t0 + 63 <= wave_minb) ATTN_CALL(false, KbufB, VbufB, t0);
          else                      ATTN_CALL(true,  KbufB, VbufB, t0);
        }
      }
      __syncthreads();
    }
  }
#undef ATTN_CALL

  // ---- epilogue: reduce l over grp (2 shuffles each), coalesced stores ----
  lsumA += __shfl_xor(lsumA, 16);
  lsumA += __shfl_xor(lsumA, 32);
  lsumB += __shfl_xor(lsumB, 16);
  lsumB += __shfl_xor(lsumB, 32);
  {
    const float inv = 1.f / lsumA;
    float* ob = out + (size_t)(bh * QQ + q0 + w * 32 + col) * DD + grp * 4;
    float4 t;
    t.x = accA0[0] * inv; t.y = accA0[1] * inv; t.z = accA0[2] * inv; t.w = accA0[3] * inv;
    *(float4*)(ob + 0) = t;
    t.x = accA1[0] * inv; t.y = accA1[1] * inv; t.z = accA1[2] * inv; t.w = accA1[3] * inv;
    *(float4*)(ob + 16) = t;
    t.x = accA2[0] * inv; t.y = accA2[1] * inv; t.z = accA2[2] * inv; t.w = accA2[3] * inv;
    *(float4*)(ob + 32) = t;
    t.x = accA3[0] * inv; t.y = accA3[1] * inv; t.z = accA3[2] * inv; t.w = accA3[3] * inv;
    *(float4*)(ob + 48) = t;
  }
  {
    const float inv = 1.f / lsumB;
    float* ob = out + (size_t)(bh * QQ + q0 + w * 32 + 16 + col) * DD + grp * 4;
    float4 t;
    t.x = accB0[0] * inv; t.y = accB0[1] * inv; t.z = accB0[2] * inv; t.w = accB0[3] * inv;
    *(float4*)(ob + 0) = t;
    t.x = accB1[0] * inv; t.y = accB1[1] * inv; t.z = accB1[2] * inv; t.w = accB1[3] * inv;
    *(float4*)(ob + 16) = t;
    t.x = accB2[0] * inv; t.y = accB2[1] * inv; t.z = accB2[2] * inv; t.w = accB2[3] * inv;
    *(float4*)(ob + 32) = t;
    t.x = accB3[0] * inv; t.y = accB3[1] * inv; t.z = accB3[2] * inv; t.w = accB3[3] * inv;
    *(float4*)(ob + 48) = t;
  }
}

// ---------------------------------------------------------------------------
// Fallback scalar path (round-1, known-good ~2.9ms) if ws too small.
// ---------------------------------------------------------------------------
__global__ __launch_bounds__(64) void attn_fb_kernel(const float* __restrict__ q,
                                                     const float* __restrict__ ksrc,
                                                     const float* __restrict__ v,
                                                     const int* __restrict__ idx,
                                                     float* __restrict__ out) {
  int t = (int)(gridDim.x - 1u - blockIdx.x);
  int sub = t >> 5;
  int bh = t & 31;
  int b = bh >> 4;
  int lane = threadIdx.x;
  int qi = sub * 64 + lane;
  const int bound = idx[b * QQ + qi];

  float qreg[64];
  {
    const float4* qp = (const float4*)(q + ((size_t)bh * QQ + qi) * DD);
#pragma unroll
    for (int i = 0; i < 16; ++i) {
      float4 t4 = qp[i];
      qreg[4 * i] = t4.x; qreg[4 * i + 1] = t4.y;
      qreg[4 * i + 2] = t4.z; qreg[4 * i + 3] = t4.w;
    }
  }
  rope32(qreg, bound);
#pragma unroll
  for (int i = 0; i < 64; ++i) qreg[i] *= 0.125f;

  const float* kbase = ksrc + (size_t)bh * SS * DD;
  const float* vbase = v + (size_t)bh * SS * DD;
  float acc[64];
#pragma unroll
  for (int i = 0; i < 64; ++i) acc[i] = 0.f;
  float mrun = -INFINITY, lrun = 0.f;

  for (int j = 0; j <= bound; ++j) {
    float ka[64];
    const float4* kp = (const float4*)(kbase + (size_t)j * DD);
#pragma unroll
    for (int i = 0; i < 16; ++i) {
      float4 t4 = kp[i];
      ka[4 * i] = t4.x; ka[4 * i + 1] = t4.y;
      ka[4 * i + 2] = t4.z; ka[4 * i + 3] = t4.w;
    }
    rope32(ka, j);
    float s0 = 0.f, s1 = 0.f, s2 = 0.f, s3 = 0.f;
#pragma unroll
    for (int i = 0; i < 16; ++i) {
      s0 = fmaf(qreg[4 * i], ka[4 * i], s0);
      s1 = fmaf(qreg[4 * i + 1], ka[4 * i + 1], s1);
      s2 = fmaf(qreg[4 * i + 2], ka[4 * i + 2], s2);
      s3 = fmaf(qreg[4 * i + 3], ka[4 * i + 3], s3);
    }
    float sc = (s0 + s1) + (s2 + s3);
    if (sc > mrun) {
      float alpha = __expf(mrun - sc);
      lrun *= alpha;
#pragma unroll
      for (int i = 0; i < 64; ++i) acc[i] *= alpha;
      mrun = sc;
    }
    float pw = __expf(sc - mrun);
    lrun += pw;
    const float4* vp = (const float4*)(vbase + (size_t)j * DD);
#pragma unroll
    for (int i = 0; i < 16; ++i) {
      float4 t4 = vp[i];
      acc[4 * i] = fmaf(pw, t4.x, acc[4 * i]);
      acc[4 * i + 1] = fmaf(pw, t4.y, acc[4 * i + 1]);
      acc[4 * i + 2] = fmaf(pw, t4.z, acc[4 * i + 2]);
      acc[4 * i + 3] = fmaf(pw, t4.w, acc[4 * i + 3]);
    }
  }
  float inv = 1.0f / lrun;
  float4* op = (float4*)(out + ((size_t)bh * QQ + qi) * DD);
#pragma unroll
  for (int i = 0; i < 16; ++i) {
    float4 t4;
    t4.x = acc[4 * i] * inv; t4.y = acc[4 * i + 1] * inv;
    t4.z = acc[4 * i + 2] * inv; t4.w = acc[4 * i + 3] * inv;
    op[i] = t4;
  }
}

extern "C" void kernel_launch(void* const* d_in, const int* in_sizes, int n_in,
                              void* d_out, int out_size, void* d_ws, size_t ws_size,
                              hipStream_t stream) {
  (void)in_sizes; (void)n_in; (void)out_size;
  const float* q = (const float*)d_in[0];
  const float* k = (const float*)d_in[1];
  const float* v = (const float*)d_in[2];
  const unsigned char* skip = (const unsigned char*)d_in[5];
  float* out = (float*)d_out;

  char* base = (char*)d_ws;
  int* idx = (int*)base;
  const size_t kbytes = (size_t)BB * HH * SS * DD * 2;
  u16* kbf = (u16*)(base + 16384);
  u16* vtb = (u16*)(base + 16384 + kbytes);
  const size_t need = 16384 + 2 * kbytes;

  prep_idx_kernel<<<2, 256, 0, stream>>>(skip, idx);
  if (ws_size >= need) {
    prep_kv_kernel<<<512 + BB * HH * 64, 256, 0, stream>>>(k, v, kbf, vtb);
    attn_mfma_kernel<<<NQT128 * 32, 256, 0, stream>>>(q, kbf, vtb, idx, out);
  } else {
    attn_fb_kernel<<<1024, 64, 0, stream>>>(q, k, v, idx, out);
  }
}

// Round 8
// 283.545 us; speedup vs baseline: 1.0505x; 1.0505x over previous
//
#include <hip/hip_runtime.h>
#include <math.h>

#define BB 2
#define HH 16
#define QQ 2048
#define SS 4096
#define DD 64
#define NRH 16    // half of N_ROTATE=32
#define NQT 32    // q-tiles of 64 per bh

typedef unsigned short u16;
typedef unsigned int   u32;
typedef short bhalf8 __attribute__((ext_vector_type(8)));  // 8 bf16 bit patterns
typedef float f32x4  __attribute__((ext_vector_type(4)));

typedef __attribute__((address_space(1))) const u32 gu32;
typedef __attribute__((address_space(3))) u32 lu32;

#if __has_builtin(__builtin_amdgcn_exp2f)
#define EXP2(x) __builtin_amdgcn_exp2f(x)
#else
#define EXP2(x) exp2f(x)
#endif

union Frag16 { uint4 u; bhalf8 v; u16 s[8]; uint2 d[2]; };

__device__ __forceinline__ u16 f2bf(float f) {  // RNE f32->bf16
  union { float f; u32 u; } c; c.f = f;
  return (u16)((c.u + 0x7FFFu + ((c.u >> 16) & 1u)) >> 16);
}

// packed RNE f32x2 -> bf16x2 (lo = first src)
__device__ __forceinline__ u32 cvt_pk_bf16(float lo, float hi) {
  u32 r;
  asm("v_cvt_pk_bf16_f32 %0, %1, %2" : "=v"(r) : "v"(lo), "v"(hi));
  return r;
}

__device__ __forceinline__ bhalf8 ldfrag(const u16* p) {
  Frag16 f; f.u = *reinterpret_cast<const uint4*>(p); return f.v;
}

__device__ __forceinline__ void rope32(float* x, int pos) {
  const float step = 0.8304820237218405f;  // log2(10000)/16
  const float fp = (float)pos;
#pragma unroll
  for (int i = 0; i < NRH; ++i) {
    float ang = fp * exp2f(-step * (float)i);
    float sv, cv;
    __sincosf(ang, &sv, &cv);
    float a = x[i], b = x[i + NRH];
    x[i]       = a * cv - b * sv;
    x[i + NRH] = b * cv + a * sv;
  }
}

// ---------------------------------------------------------------------------
// idx[b][0..2047] = ascending indices of true entries of skip_mask[b].
// Kept as standalone kernel for the fallback path; main path uses the fused
// prep kernel below.
// ---------------------------------------------------------------------------
__device__ __forceinline__ void prep_idx_body(const unsigned char* __restrict__ sm,
                                              int* __restrict__ idx, int b,
                                              int* wsum, int* modes) {
  const int tid = threadIdx.x;  // 256

  int c = 0;
  for (int i = 0; i < 32; ++i) c += (sm[tid * 32 + i] != 0) ? 1 : 0;
#pragma unroll
  for (int off = 32; off; off >>= 1) c += __shfl_down(c, off);
  if ((tid & 63) == 0) wsum[tid >> 6] = c;
  __syncthreads();
  if (tid == 0) *modes = (wsum[0] + wsum[1] + wsum[2] + wsum[3] > 3000) ? 1 : 0;
  __syncthreads();
  const bool byteMode = (*modes != 0);
  const u32* sm32 = (const u32*)sm;

  const int base = b * SS + tid * 16;
  u32 flags = 0;
  for (int i = 0; i < 16; ++i) {
    bool f = byteMode ? (sm[base + i] != 0) : (sm32[base + i] != 0);
    flags |= ((u32)(f ? 1 : 0)) << i;
  }
  int cnt = __popc(flags);
  int vv = cnt;
#pragma unroll
  for (int off = 1; off < 64; off <<= 1) {
    int t = __shfl_up(vv, off);
    if ((tid & 63) >= off) vv += t;
  }
  __syncthreads();
  if ((tid & 63) == 63) wsum[tid >> 6] = vv;
  __syncthreads();
  int add = 0;
  for (int w2 = 0; w2 < (tid >> 6); ++w2) add += wsum[w2];
  int p = vv - cnt + add;
  for (int i = 0; i < 16; ++i) {
    if (flags & (1u << i)) {
      if (p < QQ) idx[b * QQ + p] = tid * 16 + i;
      ++p;
    }
  }
}

__global__ void prep_idx_kernel(const unsigned char* __restrict__ sm,
                                int* __restrict__ idx) {
  __shared__ int wsum[4];
  __shared__ int modes;
  prep_idx_body(sm, idx, (int)blockIdx.x, wsum, &modes);
}

// ---------------------------------------------------------------------------
// FUSED prep (saves one dispatch vs separate prep_idx):
//   blocks [0,512):      k -> RoPE(pos=j) -> bf16 kbf[bh][j][d]
//   blocks [512,2560):   v -> bf16 transposed vt[bh][d][p] with key
//                        permutation kappa(p) = (p&32)|((p&4)<<2)|((p>>1)&12)|(p&3)
//                        within each 64-key tile (matches swapped-QK^T
//                        in-register P^T fragments).
//   blocks [2560,2562):  skip_mask -> idx (batch = blockIdx - 2560)
// ---------------------------------------------------------------------------
__global__ __launch_bounds__(256) void prep_fused_kernel(
    const float* __restrict__ k, const float* __restrict__ v,
    const unsigned char* __restrict__ skip,
    u16* __restrict__ kbf, u16* __restrict__ vt, int* __restrict__ idx) {
  __shared__ u16 tile[64][72];
  __shared__ int wsum[4];
  __shared__ int modes;
  if (blockIdx.x >= 2560) {
    prep_idx_body(skip, idx, (int)blockIdx.x - 2560, wsum, &modes);
  } else if (blockIdx.x < 512) {
    int r = blockIdx.x * 256 + threadIdx.x;  // 0..131071
    int pos = r & (SS - 1);
    float x[64];
    const float4* src = (const float4*)(k + (size_t)r * DD);
#pragma unroll
    for (int i = 0; i < 16; ++i) {
      float4 t = src[i];
      x[4 * i] = t.x; x[4 * i + 1] = t.y; x[4 * i + 2] = t.z; x[4 * i + 3] = t.w;
    }
    rope32(x, pos);
    u16 tmp[64];
#pragma unroll
    for (int i = 0; i < 64; ++i) tmp[i] = f2bf(x[i]);
    uint4* dst = (uint4*)(kbf + (size_t)r * DD);
#pragma unroll
    for (int i = 0; i < 8; ++i) dst[i] = ((uint4*)tmp)[i];
  } else {
    int blk = (int)blockIdx.x - 512;
    int bh = blk >> 6;
    int jt = blk & 63;
    int t = threadIdx.x;
    int jl = t >> 2;
    int dc = (t & 3) * 16;
    const float4* src = (const float4*)(v + ((size_t)(bh * SS + jt * 64 + jl)) * DD + dc);
#pragma unroll
    for (int i = 0; i < 4; ++i) {
      float4 f = src[i];
      tile[jl][dc + 4 * i]     = f2bf(f.x);
      tile[jl][dc + 4 * i + 1] = f2bf(f.y);
      tile[jl][dc + 4 * i + 2] = f2bf(f.z);
      tile[jl][dc + 4 * i + 3] = f2bf(f.w);
    }
    __syncthreads();
    int d = t >> 2;
    int c = t & 3;            // output positions c*16 .. c*16+15
    u16 o[16];
#pragma unroll
    for (int m = 0; m < 16; ++m) {  // position p holds key kappa(p)
      int p = c * 16 + m;
      int kp = (p & 32) | ((p & 4) << 2) | ((p >> 1) & 12) | (p & 3);
      o[m] = tile[kp][d];
    }
    uint4* dst = (uint4*)(vt + ((size_t)(bh * DD + d)) * SS + jt * 64 + c * 16);
    dst[0] = ((uint4*)o)[0];
    dst[1] = ((uint4*)o)[1];
  }
}

// ---------------------------------------------------------------------------
// Staging: one 64-key K tile + matching V^T tile into LDS via global_load_lds
// (16B/lane), XOR swizzle applied on the GLOBAL address side (LDS slot is the
// wave-forced contiguous one): LDS[row][c] holds global chunk c^(row&7).
// ---------------------------------------------------------------------------
__device__ __forceinline__ void stage_tiles(const char* kb_bh, const char* vt_bh,
                                            u16* Kb, u16* Vb, int t0,
                                            int w, int srow, int schk) {
#pragma unroll
  for (int p2 = 0; p2 < 2; ++p2) {
    const int rr = w * 16 + p2 * 8 + srow;
    {
      const char* g = kb_bh + (size_t)(t0 + rr) * 128 + ((schk ^ (rr & 7)) * 16);
      lu32* l = (lu32*)((char*)Kb + (w * 16 + p2 * 8) * 128);
      __builtin_amdgcn_global_load_lds((gu32*)g, l, 16, 0, 0);
    }
    {
      const char* g = vt_bh + (size_t)rr * (SS * 2) + t0 * 2 + ((schk ^ (rr & 7)) * 16);
      lu32* l = (lu32*)((char*)Vb + (w * 16 + p2 * 8) * 128);
      __builtin_amdgcn_global_load_lds((gu32*)g, l, 16, 0, 0);
    }
  }
}

// ---------------------------------------------------------------------------
// One 64-key tile, one wave, 16 q rows — SWAPPED-OPERAND form (round-6,
// verified). QK^T = mfma(A=K-frag, B=Q-frag); lane holds
// S^T[key=c*16+grp*4+r][q=col]. Softmax per-lane vs the lane's single bound,
// cvt_pk packs P^T straight into the PV B-fragment — P never touches LDS.
// PV = mfma(A=V^T-frag, B=P^T) accumulating O^T[d=grp*4+r+16c][q=col].
// ---------------------------------------------------------------------------
template <bool MASKED>
__device__ __forceinline__ void attn_tile(
    const u16* __restrict__ Kb, const u16* __restrict__ Vb,
    int t0, int grp, int col, int bnd,
    bhalf8 qa0, bhalf8 qa1,
    f32x4& acc0, f32x4& acc1, f32x4& acc2, f32x4& acc3,
    float& lsum) {
  const int swz = col & 7;
  f32x4 z = {0.f, 0.f, 0.f, 0.f};
  f32x4 s0 = z, s1 = z, s2 = z, s3 = z;
  {
    const u16* kr0 = Kb + (0 * 16 + col) * 64;
    const u16* kr1 = Kb + (1 * 16 + col) * 64;
    const u16* kr2 = Kb + (2 * 16 + col) * 64;
    const u16* kr3 = Kb + (3 * 16 + col) * 64;
    __builtin_amdgcn_s_setprio(1);
    bhalf8 a0 = ldfrag(kr0 + ((grp ^ swz) * 8));
    s0 = __builtin_amdgcn_mfma_f32_16x16x32_bf16(a0, qa0, s0, 0, 0, 0);
    bhalf8 b0 = ldfrag(kr0 + (((4 + grp) ^ swz) * 8));
    s0 = __builtin_amdgcn_mfma_f32_16x16x32_bf16(b0, qa1, s0, 0, 0, 0);
    bhalf8 a1 = ldfrag(kr1 + ((grp ^ swz) * 8));
    s1 = __builtin_amdgcn_mfma_f32_16x16x32_bf16(a1, qa0, s1, 0, 0, 0);
    bhalf8 b1 = ldfrag(kr1 + (((4 + grp) ^ swz) * 8));
    s1 = __builtin_amdgcn_mfma_f32_16x16x32_bf16(b1, qa1, s1, 0, 0, 0);
    bhalf8 a2 = ldfrag(kr2 + ((grp ^ swz) * 8));
    s2 = __builtin_amdgcn_mfma_f32_16x16x32_bf16(a2, qa0, s2, 0, 0, 0);
    bhalf8 b2 = ldfrag(kr2 + (((4 + grp) ^ swz) * 8));
    s2 = __builtin_amdgcn_mfma_f32_16x16x32_bf16(b2, qa1, s2, 0, 0, 0);
    bhalf8 a3 = ldfrag(kr3 + ((grp ^ swz) * 8));
    s3 = __builtin_amdgcn_mfma_f32_16x16x32_bf16(a3, qa0, s3, 0, 0, 0);
    bhalf8 b3 = ldfrag(kr3 + (((4 + grp) ^ swz) * 8));
    s3 = __builtin_amdgcn_mfma_f32_16x16x32_bf16(b3, qa1, s3, 0, 0, 0);
    __builtin_amdgcn_s_setprio(0);
  }

  // softmax (fixed-max exp2(s-16), exact) + pack P^T into PV B-frags in-lane
  uint2 w0, w1, w2, w3;
#define SM_C(SC, CB, W)                                                        \
  {                                                                            \
    float p0, p1, p2v, p3;                                                     \
    const int kb = t0 + (CB) + grp * 4;                                        \
    if (MASKED) {                                                              \
      p0  = (kb + 0 <= bnd) ? EXP2(SC[0] - 16.f) : 0.f;                        \
      p1  = (kb + 1 <= bnd) ? EXP2(SC[1] - 16.f) : 0.f;                        \
      p2v = (kb + 2 <= bnd) ? EXP2(SC[2] - 16.f) : 0.f;                        \
      p3  = (kb + 3 <= bnd) ? EXP2(SC[3] - 16.f) : 0.f;                        \
    } else {                                                                   \
      p0  = EXP2(SC[0] - 16.f);                                                \
      p1  = EXP2(SC[1] - 16.f);                                                \
      p2v = EXP2(SC[2] - 16.f);                                                \
      p3  = EXP2(SC[3] - 16.f);                                                \
    }                                                                          \
    lsum += (p0 + p1) + (p2v + p3);                                            \
    W.x = cvt_pk_bf16(p0, p1);                                                 \
    W.y = cvt_pk_bf16(p2v, p3);                                                \
  }
  SM_C(s0, 0,  w0)
  SM_C(s1, 16, w1)
  SM_C(s2, 32, w2)
  SM_C(s3, 48, w3)
#undef SM_C

  bhalf8 pv0, pv1;
  {
    Frag16 f0, f1;
    f0.d[0] = w0; f0.d[1] = w1;   // keys blocks 0,1  (k-slots 0..31, kappa-matched)
    f1.d[0] = w2; f1.d[1] = w3;   // keys blocks 2,3  (k-slots 32..63)
    pv0 = f0.v; pv1 = f1.v;
  }

  {
    const u16* vr0 = Vb + (0  + col) * 64;
    const u16* vr1 = Vb + (16 + col) * 64;
    const u16* vr2 = Vb + (32 + col) * 64;
    const u16* vr3 = Vb + (48 + col) * 64;
    __builtin_amdgcn_s_setprio(1);
    bhalf8 x0 = ldfrag(vr0 + ((grp ^ swz) * 8));
    acc0 = __builtin_amdgcn_mfma_f32_16x16x32_bf16(x0, pv0, acc0, 0, 0, 0);
    bhalf8 y0 = ldfrag(vr0 + (((4 + grp) ^ swz) * 8));
    acc0 = __builtin_amdgcn_mfma_f32_16x16x32_bf16(y0, pv1, acc0, 0, 0, 0);
    bhalf8 x1 = ldfrag(vr1 + ((grp ^ swz) * 8));
    acc1 = __builtin_amdgcn_mfma_f32_16x16x32_bf16(x1, pv0, acc1, 0, 0, 0);
    bhalf8 y1 = ldfrag(vr1 + (((4 + grp) ^ swz) * 8));
    acc1 = __builtin_amdgcn_mfma_f32_16x16x32_bf16(y1, pv1, acc1, 0, 0, 0);
    bhalf8 x2 = ldfrag(vr2 + ((grp ^ swz) * 8));
    acc2 = __builtin_amdgcn_mfma_f32_16x16x32_bf16(x2, pv0, acc2, 0, 0, 0);
    bhalf8 y2 = ldfrag(vr2 + (((4 + grp) ^ swz) * 8));
    acc2 = __builtin_amdgcn_mfma_f32_16x16x32_bf16(y2, pv1, acc2, 0, 0, 0);
    bhalf8 x3 = ldfrag(vr3 + ((grp ^ swz) * 8));
    acc3 = __builtin_amdgcn_mfma_f32_16x16x32_bf16(x3, pv0, acc3, 0, 0, 0);
    bhalf8 y3 = ldfrag(vr3 + (((4 + grp) ^ swz) * 8));
    acc3 = __builtin_amdgcn_mfma_f32_16x16x32_bf16(y3, pv1, acc3, 0, 0, 0);
    __builtin_amdgcn_s_setprio(0);
  }
}

// ---------------------------------------------------------------------------
// Flash attention (round-6 verified, best config). Block = 256 thr (4 waves),
// Q-tile 64 (16 q/wave), K-tile 64. Grid = 1024 (one q-tile per block,
// largest-first). LDS = 32 KiB (K/V double-buffer only — NO P buffer) ->
// 4 blocks/CU (grid-capped). Stage-before-compute dbuf loop, 1 barrier/tile.
// ---------------------------------------------------------------------------
__global__ __launch_bounds__(256, 4) void attn_mfma_kernel(
    const float* __restrict__ qsrc, const u16* __restrict__ kbf,
    const u16* __restrict__ vt, const int* __restrict__ idx,
    float* __restrict__ out) {
  __shared__ u16 KbufA[64 * 64];
  __shared__ u16 VbufA[64 * 64];
  __shared__ u16 KbufB[64 * 64];
  __shared__ u16 VbufB[64 * 64];

  const int blk = (int)blockIdx.x;   // 1024 = 32 qt-ranks x 32 bh (bh fastest)
  const int bh  = blk & 31;
  const int qt  = (NQT - 1) - (blk >> 5);  // big-first (bounds ascend with qt)
  const int q0  = qt * 64;
  const int b   = bh >> 4;
  const int tid  = threadIdx.x;
  const int w    = tid >> 6;
  const int lane = tid & 63;
  const int grp  = lane >> 4;
  const int col  = lane & 15;

  const char* kb_bh = (const char*)(kbf + (size_t)bh * SS * DD);
  const char* vt_bh = (const char*)(vt + (size_t)bh * DD * SS);

  const int srow = lane >> 3;
  const int schk = lane & 7;

  const int* idxb = idx + b * QQ + q0;
  const int bnd = idxb[w * 16 + col];      // lane's q-row bound = its RoPE pos
  const int wave_minb = idxb[w * 16];      // idx ascending -> wave min bound
  const int wave_maxb = idxb[w * 16 + 15]; // wave max bound
  const int maxbound  = idxb[63];
  const int ntiles = (maxbound >> 6) + 1;

  // ---- inline q RoPE -> fragments (round-6 verified text; pos = bnd) ----
  bhalf8 qa0, qa1;
  {
    const int qrow = q0 + w * 16 + col;
    const float* qr = qsrc + (size_t)(bh * QQ + qrow) * DD;
    const int lof = (grp & 1) * 8;
    float4 A0 = *(const float4*)(qr + lof);
    float4 A1 = *(const float4*)(qr + lof + 4);
    float4 B0 = *(const float4*)(qr + 16 + lof);
    float4 B1 = *(const float4*)(qr + 16 + lof + 4);
    float4 C0 = *(const float4*)(qr + 32 + grp * 8);
    float4 C1 = *(const float4*)(qr + 32 + grp * 8 + 4);
    float xlo[8] = {A0.x, A0.y, A0.z, A0.w, A1.x, A1.y, A1.z, A1.w};
    float xhi[8] = {B0.x, B0.y, B0.z, B0.w, B1.x, B1.y, B1.z, B1.w};
    float xq1[8] = {C0.x, C0.y, C0.z, C0.w, C1.x, C1.y, C1.z, C1.w};
    const float scq = 0.125f * 1.44269504088896f;  // 1/sqrt(64) * log2(e)
    const float fp = (float)bnd;
    Frag16 f0, f1;
#pragma unroll
    for (int j = 0; j < 8; ++j) {
      float ang = fp * exp2f(-0.8304820237218405f * (float)(lof + j));
      float sv, cv;
      __sincosf(ang, &sv, &cv);
      float val = (grp >= 2) ? (xhi[j] * cv + xlo[j] * sv)
                             : (xlo[j] * cv - xhi[j] * sv);
      f0.s[j] = f2bf(val * scq);
      f1.s[j] = f2bf(xq1[j] * scq);
    }
    qa0 = f0.v; qa1 = f1.v;
  }

  f32x4 z = {0.f, 0.f, 0.f, 0.f};
  f32x4 acc0 = z, acc1 = z, acc2 = z, acc3 = z;
  float lsum = 0.f;

#define ATTN_CALL(M, KB, VB, T0)                                               \
  attn_tile<M>(KB, VB, T0, grp, col, bnd, qa0, qa1, acc0, acc1, acc2, acc3, lsum)

  stage_tiles(kb_bh, vt_bh, KbufA, VbufA, 0, w, srow, schk);
  __syncthreads();

  for (int ti = 0; ti < ntiles; ti += 2) {
    const bool has1 = (ti + 1) < ntiles;
    if (has1) stage_tiles(kb_bh, vt_bh, KbufB, VbufB, (ti + 1) << 6, w, srow, schk);
    {
      const int t0 = ti << 6;
      if (t0 <= wave_maxb) {   // wave-uniform; skipped tiles contribute zero P
        if (t0 + 63 <= wave_minb) ATTN_CALL(false, KbufA, VbufA, t0);
        else                      ATTN_CALL(true,  KbufA, VbufA, t0);
      }
    }
    __syncthreads();
    if (has1) {
      if (ti + 2 < ntiles)
        stage_tiles(kb_bh, vt_bh, KbufA, VbufA, (ti + 2) << 6, w, srow, schk);
      {
        const int t0 = (ti + 1) << 6;
        if (t0 <= wave_maxb) {
          if (t0 + 63 <= wave_minb) ATTN_CALL(false, KbufB, VbufB, t0);
          else                      ATTN_CALL(true,  KbufB, VbufB, t0);
        }
      }
      __syncthreads();
    }
  }
#undef ATTN_CALL

  // ---- epilogue: reduce l over grp (2 shuffles), coalesced float4 stores ----
  lsum += __shfl_xor(lsum, 16);
  lsum += __shfl_xor(lsum, 32);
  const float inv = 1.f / lsum;
  float* ob = out + (size_t)(bh * QQ + q0 + w * 16 + col) * DD + grp * 4;
  {
    float4 t;
    t.x = acc0[0] * inv; t.y = acc0[1] * inv; t.z = acc0[2] * inv; t.w = acc0[3] * inv;
    *(float4*)(ob + 0) = t;
    t.x = acc1[0] * inv; t.y = acc1[1] * inv; t.z = acc1[2] * inv; t.w = acc1[3] * inv;
    *(float4*)(ob + 16) = t;
    t.x = acc2[0] * inv; t.y = acc2[1] * inv; t.z = acc2[2] * inv; t.w = acc2[3] * inv;
    *(float4*)(ob + 32) = t;
    t.x = acc3[0] * inv; t.y = acc3[1] * inv; t.z = acc3[2] * inv; t.w = acc3[3] * inv;
    *(float4*)(ob + 48) = t;
  }
}

// ---------------------------------------------------------------------------
// Fallback scalar path (round-1, known-good ~2.9ms) if ws too small.
// ---------------------------------------------------------------------------
__global__ __launch_bounds__(64) void attn_fb_kernel(const float* __restrict__ q,
                                                     const float* __restrict__ ksrc,
                                                     const float* __restrict__ v,
                                                     const int* __restrict__ idx,
                                                     float* __restrict__ out) {
  int t = (int)(gridDim.x - 1u - blockIdx.x);
  int sub = t >> 5;
  int bh = t & 31;
  int b = bh >> 4;
  int lane = threadIdx.x;
  int qi = sub * 64 + lane;
  const int bound = idx[b * QQ + qi];

  float qreg[64];
  {
    const float4* qp = (const float4*)(q + ((size_t)bh * QQ + qi) * DD);
#pragma unroll
    for (int i = 0; i < 16; ++i) {
      float4 t4 = qp[i];
      qreg[4 * i] = t4.x; qreg[4 * i + 1] = t4.y;
      qreg[4 * i + 2] = t4.z; qreg[4 * i + 3] = t4.w;
    }
  }
  rope32(qreg, bound);
#pragma unroll
  for (int i = 0; i < 64; ++i) qreg[i] *= 0.125f;

  const float* kbase = ksrc + (size_t)bh * SS * DD;
  const float* vbase = v + (size_t)bh * SS * DD;
  float acc[64];
#pragma unroll
  for (int i = 0; i < 64; ++i) acc[i] = 0.f;
  float mrun = -INFINITY, lrun = 0.f;

  for (int j = 0; j <= bound; ++j) {
    float ka[64];
    const float4* kp = (const float4*)(kbase + (size_t)j * DD);
#pragma unroll
    for (int i = 0; i < 16; ++i) {
      float4 t4 = kp[i];
      ka[4 * i] = t4.x; ka[4 * i + 1] = t4.y;
      ka[4 * i + 2] = t4.z; ka[4 * i + 3] = t4.w;
    }
    rope32(ka, j);
    float s0 = 0.f, s1 = 0.f, s2 = 0.f, s3 = 0.f;
#pragma unroll
    for (int i = 0; i < 16; ++i) {
      s0 = fmaf(qreg[4 * i], ka[4 * i], s0);
      s1 = fmaf(qreg[4 * i + 1], ka[4 * i + 1], s1);
      s2 = fmaf(qreg[4 * i + 2], ka[4 * i + 2], s2);
      s3 = fmaf(qreg[4 * i + 3], ka[4 * i + 3], s3);
    }
    float sc = (s0 + s1) + (s2 + s3);
    if (sc > mrun) {
      float alpha = __expf(mrun - sc);
      lrun *= alpha;
#pragma unroll
      for (int i = 0; i < 64; ++i) acc[i] *= alpha;
      mrun = sc;
    }
    float pw = __expf(sc - mrun);
    lrun += pw;
    const float4* vp = (const float4*)(vbase + (size_t)j * DD);
#pragma unroll
    for (int i = 0; i < 16; ++i) {
      float4 t4 = vp[i];
      acc[4 * i] = fmaf(pw, t4.x, acc[4 * i]);
      acc[4 * i + 1] = fmaf(pw, t4.y, acc[4 * i + 1]);
      acc[4 * i + 2] = fmaf(pw, t4.z, acc[4 * i + 2]);
      acc[4 * i + 3] = fmaf(pw, t4.w, acc[4 * i + 3]);
    }
  }
  float inv = 1.0f / lrun;
  float4* op = (float4*)(out + ((size_t)bh * QQ + qi) * DD);
#pragma unroll
  for (int i = 0; i < 16; ++i) {
    float4 t4;
    t4.x = acc[4 * i] * inv; t4.y = acc[4 * i + 1] * inv;
    t4.z = acc[4 * i + 2] * inv; t4.w = acc[4 * i + 3] * inv;
    op[i] = t4;
  }
}

extern "C" void kernel_launch(void* const* d_in, const int* in_sizes, int n_in,
                              void* d_out, int out_size, void* d_ws, size_t ws_size,
                              hipStream_t stream) {
  (void)in_sizes; (void)n_in; (void)out_size;
  const float* q = (const float*)d_in[0];
  const float* k = (const float*)d_in[1];
  const float* v = (const float*)d_in[2];
  const unsigned char* skip = (const unsigned char*)d_in[5];
  float* out = (float*)d_out;

  char* base = (char*)d_ws;
  int* idx = (int*)base;
  const size_t kbytes = (size_t)BB * HH * SS * DD * 2;
  u16* kbf = (u16*)(base + 16384);
  u16* vtb = (u16*)(base + 16384 + kbytes);
  const size_t need = 16384 + 2 * kbytes;

  if (ws_size >= need) {
    prep_fused_kernel<<<512 + BB * HH * 64 + BB, 256, 0, stream>>>(k, v, skip,
                                                                   kbf, vtb, idx);
    attn_mfma_kernel<<<NQT * 32, 256, 0, stream>>>(q, kbf, vtb, idx, out);
  } else {
    prep_idx_kernel<<<2, 256, 0, stream>>>(skip, idx);
    attn_fb_kernel<<<1024, 64, 0, stream>>>(q, k, v, idx, out);
  }
}

// Round 9
// 282.785 us; speedup vs baseline: 1.0533x; 1.0027x over previous
//
#include <hip/hip_runtime.h>
#include <math.h>

#define BB 2
#define HH 16
#define QQ 2048
#define SS 4096
#define DD 64
#define NRH 16    // half of N_ROTATE=32
#define NQT 32    // q-tiles of 64 per bh

typedef unsigned short u16;
typedef unsigned int   u32;
typedef short bhalf8 __attribute__((ext_vector_type(8)));  // 8 bf16 bit patterns
typedef float f32x4  __attribute__((ext_vector_type(4)));

typedef __attribute__((address_space(1))) const u32 gu32;
typedef __attribute__((address_space(3))) u32 lu32;

#if __has_builtin(__builtin_amdgcn_exp2f)
#define EXP2(x) __builtin_amdgcn_exp2f(x)
#else
#define EXP2(x) exp2f(x)
#endif

union Frag16 { uint4 u; bhalf8 v; u16 s[8]; uint2 d[2]; };

__device__ __forceinline__ u16 f2bf(float f) {  // RNE f32->bf16
  union { float f; u32 u; } c; c.f = f;
  return (u16)((c.u + 0x7FFFu + ((c.u >> 16) & 1u)) >> 16);
}

// packed RNE f32x2 -> bf16x2 (lo = first src)
__device__ __forceinline__ u32 cvt_pk_bf16(float lo, float hi) {
  u32 r;
  asm("v_cvt_pk_bf16_f32 %0, %1, %2" : "=v"(r) : "v"(lo), "v"(hi));
  return r;
}

__device__ __forceinline__ bhalf8 ldfrag(const u16* p) {
  Frag16 f; f.u = *reinterpret_cast<const uint4*>(p); return f.v;
}

__device__ __forceinline__ void rope32(float* x, int pos) {
  const float step = 0.8304820237218405f;  // log2(10000)/16
  const float fp = (float)pos;
#pragma unroll
  for (int i = 0; i < NRH; ++i) {
    float ang = fp * exp2f(-step * (float)i);
    float sv, cv;
    __sincosf(ang, &sv, &cv);
    float a = x[i], b = x[i + NRH];
    x[i]       = a * cv - b * sv;
    x[i + NRH] = b * cv + a * sv;
  }
}

// ---------------------------------------------------------------------------
// idx[b][0..2047] = ascending indices of true entries of skip_mask[b].
// Kept as standalone kernel for the fallback path; main path uses the fused
// prep kernel below.
// ---------------------------------------------------------------------------
__device__ __forceinline__ void prep_idx_body(const unsigned char* __restrict__ sm,
                                              int* __restrict__ idx, int b,
                                              int* wsum, int* modes) {
  const int tid = threadIdx.x;  // 256

  int c = 0;
  for (int i = 0; i < 32; ++i) c += (sm[tid * 32 + i] != 0) ? 1 : 0;
#pragma unroll
  for (int off = 32; off; off >>= 1) c += __shfl_down(c, off);
  if ((tid & 63) == 0) wsum[tid >> 6] = c;
  __syncthreads();
  if (tid == 0) *modes = (wsum[0] + wsum[1] + wsum[2] + wsum[3] > 3000) ? 1 : 0;
  __syncthreads();
  const bool byteMode = (*modes != 0);
  const u32* sm32 = (const u32*)sm;

  const int base = b * SS + tid * 16;
  u32 flags = 0;
  for (int i = 0; i < 16; ++i) {
    bool f = byteMode ? (sm[base + i] != 0) : (sm32[base + i] != 0);
    flags |= ((u32)(f ? 1 : 0)) << i;
  }
  int cnt = __popc(flags);
  int vv = cnt;
#pragma unroll
  for (int off = 1; off < 64; off <<= 1) {
    int t = __shfl_up(vv, off);
    if ((tid & 63) >= off) vv += t;
  }
  __syncthreads();
  if ((tid & 63) == 63) wsum[tid >> 6] = vv;
  __syncthreads();
  int add = 0;
  for (int w2 = 0; w2 < (tid >> 6); ++w2) add += wsum[w2];
  int p = vv - cnt + add;
  for (int i = 0; i < 16; ++i) {
    if (flags & (1u << i)) {
      if (p < QQ) idx[b * QQ + p] = tid * 16 + i;
      ++p;
    }
  }
}

__global__ void prep_idx_kernel(const unsigned char* __restrict__ sm,
                                int* __restrict__ idx) {
  __shared__ int wsum[4];
  __shared__ int modes;
  prep_idx_body(sm, idx, (int)blockIdx.x, wsum, &modes);
}

// ---------------------------------------------------------------------------
// FUSED prep (saves one dispatch vs separate prep_idx):
//   blocks [0,512):      k -> RoPE(pos=j) -> bf16 kbf[bh][j][d]
//   blocks [512,2560):   v -> bf16 transposed vt[bh][d][p] with key
//                        permutation kappa(p) = (p&32)|((p&4)<<2)|((p>>1)&12)|(p&3)
//                        within each 64-key tile (matches swapped-QK^T
//                        in-register P^T fragments).
//   blocks [2560,2562):  skip_mask -> idx (batch = blockIdx - 2560)
// ---------------------------------------------------------------------------
__global__ __launch_bounds__(256) void prep_fused_kernel(
    const float* __restrict__ k, const float* __restrict__ v,
    const unsigned char* __restrict__ skip,
    u16* __restrict__ kbf, u16* __restrict__ vt, int* __restrict__ idx) {
  __shared__ u16 tile[64][72];
  __shared__ int wsum[4];
  __shared__ int modes;
  if (blockIdx.x >= 2560) {
    prep_idx_body(skip, idx, (int)blockIdx.x - 2560, wsum, &modes);
  } else if (blockIdx.x < 512) {
    int r = blockIdx.x * 256 + threadIdx.x;  // 0..131071
    int pos = r & (SS - 1);
    float x[64];
    const float4* src = (const float4*)(k + (size_t)r * DD);
#pragma unroll
    for (int i = 0; i < 16; ++i) {
      float4 t = src[i];
      x[4 * i] = t.x; x[4 * i + 1] = t.y; x[4 * i + 2] = t.z; x[4 * i + 3] = t.w;
    }
    rope32(x, pos);
    u16 tmp[64];
#pragma unroll
    for (int i = 0; i < 64; ++i) tmp[i] = f2bf(x[i]);
    uint4* dst = (uint4*)(kbf + (size_t)r * DD);
#pragma unroll
    for (int i = 0; i < 8; ++i) dst[i] = ((uint4*)tmp)[i];
  } else {
    int blk = (int)blockIdx.x - 512;
    int bh = blk >> 6;
    int jt = blk & 63;
    int t = threadIdx.x;
    int jl = t >> 2;
    int dc = (t & 3) * 16;
    const float4* src = (const float4*)(v + ((size_t)(bh * SS + jt * 64 + jl)) * DD + dc);
#pragma unroll
    for (int i = 0; i < 4; ++i) {
      float4 f = src[i];
      tile[jl][dc + 4 * i]     = f2bf(f.x);
      tile[jl][dc + 4 * i + 1] = f2bf(f.y);
      tile[jl][dc + 4 * i + 2] = f2bf(f.z);
      tile[jl][dc + 4 * i + 3] = f2bf(f.w);
    }
    __syncthreads();
    int d = t >> 2;
    int c = t & 3;            // output positions c*16 .. c*16+15
    u16 o[16];
#pragma unroll
    for (int m = 0; m < 16; ++m) {  // position p holds key kappa(p)
      int p = c * 16 + m;
      int kp = (p & 32) | ((p & 4) << 2) | ((p >> 1) & 12) | (p & 3);
      o[m] = tile[kp][d];
    }
    uint4* dst = (uint4*)(vt + ((size_t)(bh * DD + d)) * SS + jt * 64 + c * 16);
    dst[0] = ((uint4*)o)[0];
    dst[1] = ((uint4*)o)[1];
  }
}

// ---------------------------------------------------------------------------
// Staging: one 64-key K tile + matching V^T tile into LDS via global_load_lds
// (16B/lane), XOR swizzle applied on the GLOBAL address side (LDS slot is the
// wave-forced contiguous one): LDS[row][c] holds global chunk c^(row&7).
// ---------------------------------------------------------------------------
__device__ __forceinline__ void stage_tiles(const char* kb_bh, const char* vt_bh,
                                            u16* Kb, u16* Vb, int t0,
                                            int w, int srow, int schk) {
#pragma unroll
  for (int p2 = 0; p2 < 2; ++p2) {
    const int rr = w * 16 + p2 * 8 + srow;
    {
      const char* g = kb_bh + (size_t)(t0 + rr) * 128 + ((schk ^ (rr & 7)) * 16);
      lu32* l = (lu32*)((char*)Kb + (w * 16 + p2 * 8) * 128);
      __builtin_amdgcn_global_load_lds((gu32*)g, l, 16, 0, 0);
    }
    {
      const char* g = vt_bh + (size_t)rr * (SS * 2) + t0 * 2 + ((schk ^ (rr & 7)) * 16);
      lu32* l = (lu32*)((char*)Vb + (w * 16 + p2 * 8) * 128);
      __builtin_amdgcn_global_load_lds((gu32*)g, l, 16, 0, 0);
    }
  }
}

// ---------------------------------------------------------------------------
// One 64-key tile, one wave, 16 q rows — SWAPPED-OPERAND form (round-6,
// verified). QK^T = mfma(A=K-frag, B=Q-frag); lane holds
// S^T[key=c*16+grp*4+r][q=col]. Softmax per-lane vs the lane's single bound,
// cvt_pk packs P^T straight into the PV B-fragment — P never touches LDS.
// PV = mfma(A=V^T-frag, B=P^T) accumulating O^T[d=grp*4+r+16c][q=col].
// ---------------------------------------------------------------------------
template <bool MASKED>
__device__ __forceinline__ void attn_tile(
    const u16* __restrict__ Kb, const u16* __restrict__ Vb,
    int t0, int grp, int col, int bnd,
    bhalf8 qa0, bhalf8 qa1,
    f32x4& acc0, f32x4& acc1, f32x4& acc2, f32x4& acc3,
    float& lsum) {
  const int swz = col & 7;
  f32x4 z = {0.f, 0.f, 0.f, 0.f};
  f32x4 s0 = z, s1 = z, s2 = z, s3 = z;
  {
    const u16* kr0 = Kb + (0 * 16 + col) * 64;
    const u16* kr1 = Kb + (1 * 16 + col) * 64;
    const u16* kr2 = Kb + (2 * 16 + col) * 64;
    const u16* kr3 = Kb + (3 * 16 + col) * 64;
    __builtin_amdgcn_s_setprio(1);
    bhalf8 a0 = ldfrag(kr0 + ((grp ^ swz) * 8));
    s0 = __builtin_amdgcn_mfma_f32_16x16x32_bf16(a0, qa0, s0, 0, 0, 0);
    bhalf8 b0 = ldfrag(kr0 + (((4 + grp) ^ swz) * 8));
    s0 = __builtin_amdgcn_mfma_f32_16x16x32_bf16(b0, qa1, s0, 0, 0, 0);
    bhalf8 a1 = ldfrag(kr1 + ((grp ^ swz) * 8));
    s1 = __builtin_amdgcn_mfma_f32_16x16x32_bf16(a1, qa0, s1, 0, 0, 0);
    bhalf8 b1 = ldfrag(kr1 + (((4 + grp) ^ swz) * 8));
    s1 = __builtin_amdgcn_mfma_f32_16x16x32_bf16(b1, qa1, s1, 0, 0, 0);
    bhalf8 a2 = ldfrag(kr2 + ((grp ^ swz) * 8));
    s2 = __builtin_amdgcn_mfma_f32_16x16x32_bf16(a2, qa0, s2, 0, 0, 0);
    bhalf8 b2 = ldfrag(kr2 + (((4 + grp) ^ swz) * 8));
    s2 = __builtin_amdgcn_mfma_f32_16x16x32_bf16(b2, qa1, s2, 0, 0, 0);
    bhalf8 a3 = ldfrag(kr3 + ((grp ^ swz) * 8));
    s3 = __builtin_amdgcn_mfma_f32_16x16x32_bf16(a3, qa0, s3, 0, 0, 0);
    bhalf8 b3 = ldfrag(kr3 + (((4 + grp) ^ swz) * 8));
    s3 = __builtin_amdgcn_mfma_f32_16x16x32_bf16(b3, qa1, s3, 0, 0, 0);
    __builtin_amdgcn_s_setprio(0);
  }

  // softmax (fixed-max exp2(s-16), exact) + pack P^T into PV B-frags in-lane
  uint2 w0, w1, w2, w3;
#define SM_C(SC, CB, W)                                                        \
  {                                                                            \
    float p0, p1, p2v, p3;                                                     \
    const int kb = t0 + (CB) + grp * 4;                                        \
    if (MASKED) {                                                              \
      p0  = (kb + 0 <= bnd) ? EXP2(SC[0] - 16.f) : 0.f;                        \
      p1  = (kb + 1 <= bnd) ? EXP2(SC[1] - 16.f) : 0.f;                        \
      p2v = (kb + 2 <= bnd) ? EXP2(SC[2] - 16.f) : 0.f;                        \
      p3  = (kb + 3 <= bnd) ? EXP2(SC[3] - 16.f) : 0.f;                        \
    } else {                                                                   \
      p0  = EXP2(SC[0] - 16.f);                                                \
      p1  = EXP2(SC[1] - 16.f);                                                \
      p2v = EXP2(SC[2] - 16.f);                                                \
      p3  = EXP2(SC[3] - 16.f);                                                \
    }                                                                          \
    lsum += (p0 + p1) + (p2v + p3);                                            \
    W.x = cvt_pk_bf16(p0, p1);                                                 \
    W.y = cvt_pk_bf16(p2v, p3);                                                \
  }
  SM_C(s0, 0,  w0)
  SM_C(s1, 16, w1)
  SM_C(s2, 32, w2)
  SM_C(s3, 48, w3)
#undef SM_C

  bhalf8 pv0, pv1;
  {
    Frag16 f0, f1;
    f0.d[0] = w0; f0.d[1] = w1;   // keys blocks 0,1  (k-slots 0..31, kappa-matched)
    f1.d[0] = w2; f1.d[1] = w3;   // keys blocks 2,3  (k-slots 32..63)
    pv0 = f0.v; pv1 = f1.v;
  }

  {
    const u16* vr0 = Vb + (0  + col) * 64;
    const u16* vr1 = Vb + (16 + col) * 64;
    const u16* vr2 = Vb + (32 + col) * 64;
    const u16* vr3 = Vb + (48 + col) * 64;
    __builtin_amdgcn_s_setprio(1);
    bhalf8 x0 = ldfrag(vr0 + ((grp ^ swz) * 8));
    acc0 = __builtin_amdgcn_mfma_f32_16x16x32_bf16(x0, pv0, acc0, 0, 0, 0);
    bhalf8 y0 = ldfrag(vr0 + (((4 + grp) ^ swz) * 8));
    acc0 = __builtin_amdgcn_mfma_f32_16x16x32_bf16(y0, pv1, acc0, 0, 0, 0);
    bhalf8 x1 = ldfrag(vr1 + ((grp ^ swz) * 8));
    acc1 = __builtin_amdgcn_mfma_f32_16x16x32_bf16(x1, pv0, acc1, 0, 0, 0);
    bhalf8 y1 = ldfrag(vr1 + (((4 + grp) ^ swz) * 8));
    acc1 = __builtin_amdgcn_mfma_f32_16x16x32_bf16(y1, pv1, acc1, 0, 0, 0);
    bhalf8 x2 = ldfrag(vr2 + ((grp ^ swz) * 8));
    acc2 = __builtin_amdgcn_mfma_f32_16x16x32_bf16(x2, pv0, acc2, 0, 0, 0);
    bhalf8 y2 = ldfrag(vr2 + (((4 + grp) ^ swz) * 8));
    acc2 = __builtin_amdgcn_mfma_f32_16x16x32_bf16(y2, pv1, acc2, 0, 0, 0);
    bhalf8 x3 = ldfrag(vr3 + ((grp ^ swz) * 8));
    acc3 = __builtin_amdgcn_mfma_f32_16x16x32_bf16(x3, pv0, acc3, 0, 0, 0);
    bhalf8 y3 = ldfrag(vr3 + (((4 + grp) ^ swz) * 8));
    acc3 = __builtin_amdgcn_mfma_f32_16x16x32_bf16(y3, pv1, acc3, 0, 0, 0);
    __builtin_amdgcn_s_setprio(0);
  }
}

// ---------------------------------------------------------------------------
// Flash attention (round-6 verified structure). Block = 256 thr (4 waves),
// Q-tile 64 (16 q/wave), K-tile 64. Grid = 1024 — ALL blocks resident
// (4/CU exactly), so the static block->CU assignment is final: CU gets
// ranks {r, r+8, r+16, r+24}. The rank->qt map below makes every such
// column's total work constant (sum of (qt+1) = 66 for all r) — removes
// the 52..80 per-CU imbalance of the old 31-rank map.
// LDS = 32 KiB (K/V dbuf only, no P buffer). 1 barrier/tile.
// ---------------------------------------------------------------------------
__global__ __launch_bounds__(256, 4) void attn_mfma_kernel(
    const float* __restrict__ qsrc, const u16* __restrict__ kbf,
    const u16* __restrict__ vt, const int* __restrict__ idx,
    float* __restrict__ out) {
  __shared__ u16 KbufA[64 * 64];
  __shared__ u16 VbufA[64 * 64];
  __shared__ u16 KbufB[64 * 64];
  __shared__ u16 VbufB[64 * 64];

  const int blk = (int)blockIdx.x;   // 1024 = 32 qt-ranks x 32 bh (bh fastest)
  const int bh  = blk & 31;
  const int rank = blk >> 5;         // 0..31
  const int rmod = rank & 7;
  const int rdiv = rank >> 3;        // 0..3
  // column-balanced map: {31-rmod, rmod, 23-rmod, 8+rmod} — each column
  // {r, r+8, r+16, r+24} sums (qt+1) to 66; bijective over 0..31.
  const int qt = (rdiv == 0) ? (31 - rmod)
               : (rdiv == 1) ? rmod
               : (rdiv == 2) ? (23 - rmod)
               : (8 + rmod);
  const int q0  = qt * 64;
  const int b   = bh >> 4;
  const int tid  = threadIdx.x;
  const int w    = tid >> 6;
  const int lane = tid & 63;
  const int grp  = lane >> 4;
  const int col  = lane & 15;

  const char* kb_bh = (const char*)(kbf + (size_t)bh * SS * DD);
  const char* vt_bh = (const char*)(vt + (size_t)bh * DD * SS);

  const int srow = lane >> 3;
  const int schk = lane & 7;

  const int* idxb = idx + b * QQ + q0;
  const int bnd = idxb[w * 16 + col];      // lane's q-row bound = its RoPE pos
  const int wave_minb = idxb[w * 16];      // idx ascending -> wave min bound
  const int wave_maxb = idxb[w * 16 + 15]; // wave max bound
  const int maxbound  = idxb[63];
  const int ntiles = (maxbound >> 6) + 1;

  // ---- inline q RoPE -> fragments (round-6 verified text; pos = bnd) ----
  bhalf8 qa0, qa1;
  {
    const int qrow = q0 + w * 16 + col;
    const float* qr = qsrc + (size_t)(bh * QQ + qrow) * DD;
    const int lof = (grp & 1) * 8;
    float4 A0 = *(const float4*)(qr + lof);
    float4 A1 = *(const float4*)(qr + lof + 4);
    float4 B0 = *(const float4*)(qr + 16 + lof);
    float4 B1 = *(const float4*)(qr + 16 + lof + 4);
    float4 C0 = *(const float4*)(qr + 32 + grp * 8);
    float4 C1 = *(const float4*)(qr + 32 + grp * 8 + 4);
    float xlo[8] = {A0.x, A0.y, A0.z, A0.w, A1.x, A1.y, A1.z, A1.w};
    float xhi[8] = {B0.x, B0.y, B0.z, B0.w, B1.x, B1.y, B1.z, B1.w};
    float xq1[8] = {C0.x, C0.y, C0.z, C0.w, C1.x, C1.y, C1.z, C1.w};
    const float scq = 0.125f * 1.44269504088896f;  // 1/sqrt(64) * log2(e)
    const float fp = (float)bnd;
    Frag16 f0, f1;
#pragma unroll
    for (int j = 0; j < 8; ++j) {
      float ang = fp * exp2f(-0.8304820237218405f * (float)(lof + j));
      float sv, cv;
      __sincosf(ang, &sv, &cv);
      float val = (grp >= 2) ? (xhi[j] * cv + xlo[j] * sv)
                             : (xlo[j] * cv - xhi[j] * sv);
      f0.s[j] = f2bf(val * scq);
      f1.s[j] = f2bf(xq1[j] * scq);
    }
    qa0 = f0.v; qa1 = f1.v;
  }

  f32x4 z = {0.f, 0.f, 0.f, 0.f};
  f32x4 acc0 = z, acc1 = z, acc2 = z, acc3 = z;
  float lsum = 0.f;

#define ATTN_CALL(M, KB, VB, T0)                                               \
  attn_tile<M>(KB, VB, T0, grp, col, bnd, qa0, qa1, acc0, acc1, acc2, acc3, lsum)

  stage_tiles(kb_bh, vt_bh, KbufA, VbufA, 0, w, srow, schk);
  __syncthreads();

  for (int ti = 0; ti < ntiles; ti += 2) {
    const bool has1 = (ti + 1) < ntiles;
    if (has1) stage_tiles(kb_bh, vt_bh, KbufB, VbufB, (ti + 1) << 6, w, srow, schk);
    {
      const int t0 = ti << 6;
      if (t0 <= wave_maxb) {   // wave-uniform; skipped tiles contribute zero P
        if (t0 + 63 <= wave_minb) ATTN_CALL(false, KbufA, VbufA, t0);
        else                      ATTN_CALL(true,  KbufA, VbufA, t0);
      }
    }
    __syncthreads();
    if (has1) {
      if (ti + 2 < ntiles)
        stage_tiles(kb_bh, vt_bh, KbufA, VbufA, (ti + 2) << 6, w, srow, schk);
      {
        const int t0 = (ti + 1) << 6;
        if (t0 <= wave_maxb) {
          if (t0 + 63 <= wave_minb) ATTN_CALL(false, KbufB, VbufB, t0);
          else                      ATTN_CALL(true,  KbufB, VbufB, t0);
        }
      }
      __syncthreads();
    }
  }
#undef ATTN_CALL

  // ---- epilogue: reduce l over grp (2 shuffles), coalesced float4 stores ----
  lsum += __shfl_xor(lsum, 16);
  lsum += __shfl_xor(lsum, 32);
  const float inv = 1.f / lsum;
  float* ob = out + (size_t)(bh * QQ + q0 + w * 16 + col) * DD + grp * 4;
  {
    float4 t;
    t.x = acc0[0] * inv; t.y = acc0[1] * inv; t.z = acc0[2] * inv; t.w = acc0[3] * inv;
    *(float4*)(ob + 0) = t;
    t.x = acc1[0] * inv; t.y = acc1[1] * inv; t.z = acc1[2] * inv; t.w = acc1[3] * inv;
    *(float4*)(ob + 16) = t;
    t.x = acc2[0] * inv; t.y = acc2[1] * inv; t.z = acc2[2] * inv; t.w = acc2[3] * inv;
    *(float4*)(ob + 32) = t;
    t.x = acc3[0] * inv; t.y = acc3[1] * inv; t.z = acc3[2] * inv; t.w = acc3[3] * inv;
    *(float4*)(ob + 48) = t;
  }
}

// ---------------------------------------------------------------------------
// Fallback scalar path (round-1, known-good ~2.9ms) if ws too small.
// ---------------------------------------------------------------------------
__global__ __launch_bounds__(64) void attn_fb_kernel(const float* __restrict__ q,
                                                     const float* __restrict__ ksrc,
                                                     const float* __restrict__ v,
                                                     const int* __restrict__ idx,
                                                     float* __restrict__ out) {
  int t = (int)(gridDim.x - 1u - blockIdx.x);
  int sub = t >> 5;
  int bh = t & 31;
  int b = bh >> 4;
  int lane = threadIdx.x;
  int qi = sub * 64 + lane;
  const int bound = idx[b * QQ + qi];

  float qreg[64];
  {
    const float4* qp = (const float4*)(q + ((size_t)bh * QQ + qi) * DD);
#pragma unroll
    for (int i = 0; i < 16; ++i) {
      float4 t4 = qp[i];
      qreg[4 * i] = t4.x; qreg[4 * i + 1] = t4.y;
      qreg[4 * i + 2] = t4.z; qreg[4 * i + 3] = t4.w;
    }
  }
  rope32(qreg, bound);
#pragma unroll
  for (int i = 0; i < 64; ++i) qreg[i] *= 0.125f;

  const float* kbase = ksrc + (size_t)bh * SS * DD;
  const float* vbase = v + (size_t)bh * SS * DD;
  float acc[64];
#pragma unroll
  for (int i = 0; i < 64; ++i) acc[i] = 0.f;
  float mrun = -INFINITY, lrun = 0.f;

  for (int j = 0; j <= bound; ++j) {
    float ka[64];
    const float4* kp = (const float4*)(kbase + (size_t)j * DD);
#pragma unroll
    for (int i = 0; i < 16; ++i) {
      float4 t4 = kp[i];
      ka[4 * i] = t4.x; ka[4 * i + 1] = t4.y;
      ka[4 * i + 2] = t4.z; ka[4 * i + 3] = t4.w;
    }
    rope32(ka, j);
    float s0 = 0.f, s1 = 0.f, s2 = 0.f, s3 = 0.f;
#pragma unroll
    for (int i = 0; i < 16; ++i) {
      s0 = fmaf(qreg[4 * i], ka[4 * i], s0);
      s1 = fmaf(qreg[4 * i + 1], ka[4 * i + 1], s1);
      s2 = fmaf(qreg[4 * i + 2], ka[4 * i + 2], s2);
      s3 = fmaf(qreg[4 * i + 3], ka[4 * i + 3], s3);
    }
    float sc = (s0 + s1) + (s2 + s3);
    if (sc > mrun) {
      float alpha = __expf(mrun - sc);
      lrun *= alpha;
#pragma unroll
      for (int i = 0; i < 64; ++i) acc[i] *= alpha;
      mrun = sc;
    }
    float pw = __expf(sc - mrun);
    lrun += pw;
    const float4* vp = (const float4*)(vbase + (size_t)j * DD);
#pragma unroll
    for (int i = 0; i < 16; ++i) {
      float4 t4 = vp[i];
      acc[4 * i] = fmaf(pw, t4.x, acc[4 * i]);
      acc[4 * i + 1] = fmaf(pw, t4.y, acc[4 * i + 1]);
      acc[4 * i + 2] = fmaf(pw, t4.z, acc[4 * i + 2]);
      acc[4 * i + 3] = fmaf(pw, t4.w, acc[4 * i + 3]);
    }
  }
  float inv = 1.0f / lrun;
  float4* op = (float4*)(out + ((size_t)bh * QQ + qi) * DD);
#pragma unroll
  for (int i = 0; i < 16; ++i) {
    float4 t4;
    t4.x = acc[4 * i] * inv; t4.y = acc[4 * i + 1] * inv;
    t4.z = acc[4 * i + 2] * inv; t4.w = acc[4 * i + 3] * inv;
    op[i] = t4;
  }
}

extern "C" void kernel_launch(void* const* d_in, const int* in_sizes, int n_in,
                              void* d_out, int out_size, void* d_ws, size_t ws_size,
                              hipStream_t stream) {
  (void)in_sizes; (void)n_in; (void)out_size;
  const float* q = (const float*)d_in[0];
  const float* k = (const float*)d_in[1];
  const float* v = (const float*)d_in[2];
  const unsigned char* skip = (const unsigned char*)d_in[5];
  float* out = (float*)d_out;

  char* base = (char*)d_ws;
  int* idx = (int*)base;
  const size_t kbytes = (size_t)BB * HH * SS * DD * 2;
  u16* kbf = (u16*)(base + 16384);
  u16* vtb = (u16*)(base + 16384 + kbytes);
  const size_t need = 16384 + 2 * kbytes;

  if (ws_size >= need) {
    prep_fused_kernel<<<512 + BB * HH * 64 + BB, 256, 0, stream>>>(k, v, skip,
                                                                   kbf, vtb, idx);
    attn_mfma_kernel<<<NQT * 32, 256, 0, stream>>>(q, kbf, vtb, idx, out);
  } else {
    prep_idx_kernel<<<2, 256, 0, stream>>>(skip, idx);
    attn_fb_kernel<<<1024, 64, 0, stream>>>(q, k, v, idx, out);
  }
}